// Round 3
// baseline (6891.087 us; speedup 1.0000x reference)
//
#include <hip/hip_runtime.h>
#include <math.h>

// Problem constants
#define NPTS   65536
#define NBATCH 4
#define KCP    1024      // NCP centers
#define DM     256
#define FFD    1024
#define EDIM   8192      // E
#define N3E    24576     // 3*E

// FPS decomposition: 16 blocks/batch x 256 threads (4 waves); 64 publisher-waves
// per batch, each wave owns 1024 points (16/thread) held in registers.
#define FPS_NBLK 16
#define FPS_THR  256
#define FPS_PPT  16

__device__ __forceinline__ unsigned long long umaxll(unsigned long long a, unsigned long long b) {
  return a > b ? a : b;
}

// ---------------------------------------------------------------- global min/max (for L)
__global__ __launch_bounds__(256) void redmm_kernel(const float* __restrict__ v, int n,
                                                    float* __restrict__ pmax, float* __restrict__ pmin) {
  float mx = -INFINITY, mn = INFINITY;
  for (int i = blockIdx.x * 256 + threadIdx.x; i < n; i += gridDim.x * 256) {
    float x = v[i]; mx = fmaxf(mx, x); mn = fminf(mn, x);
  }
#pragma unroll
  for (int off = 32; off >= 1; off >>= 1) {
    mx = fmaxf(mx, __shfl_xor(mx, off, 64));
    mn = fminf(mn, __shfl_xor(mn, off, 64));
  }
  __shared__ float smx[4], smn[4];
  int lane = threadIdx.x & 63, w = threadIdx.x >> 6;
  if (lane == 0) { smx[w] = mx; smn[w] = mn; }
  __syncthreads();
  if (threadIdx.x == 0) {
    pmax[blockIdx.x] = fmaxf(fmaxf(smx[0], smx[1]), fmaxf(smx[2], smx[3]));
    pmin[blockIdx.x] = fminf(fminf(smn[0], smn[1]), fminf(smn[2], smn[3]));
  }
}

__global__ __launch_bounds__(256) void redfin_kernel(const float* __restrict__ pmax,
                                                     const float* __restrict__ pmin, int nb,
                                                     float* __restrict__ Lv) {
  float mx = -INFINITY, mn = INFINITY;
  for (int i = threadIdx.x; i < nb; i += 256) { mx = fmaxf(mx, pmax[i]); mn = fminf(mn, pmin[i]); }
#pragma unroll
  for (int off = 32; off >= 1; off >>= 1) {
    mx = fmaxf(mx, __shfl_xor(mx, off, 64));
    mn = fminf(mn, __shfl_xor(mn, off, 64));
  }
  __shared__ float smx[4], smn[4];
  int lane = threadIdx.x & 63, w = threadIdx.x >> 6;
  if (lane == 0) { smx[w] = mx; smn[w] = mn; }
  __syncthreads();
  if (threadIdx.x == 0) {
    mx = fmaxf(fmaxf(smx[0], smx[1]), fmaxf(smx[2], smx[3]));
    mn = fminf(fminf(smn[0], smn[1]), fminf(smn[2], smn[3]));
    Lv[0] = __fsub_rn(mx, mn);
  }
}

// ---------------------------------------------------------------- FPS (density seed + 1023 rounds)
// Wave-autonomous relaxed mailbox: 64 publisher-waves per batch. Per round each
// wave reduces its 1024 points in-register, publishes ONE 8-byte packed key
// (relaxed agent atomic store, no fences), polls all 64 keys (one per lane,
// relaxed atomic loads), reduces the winner, re-gathers xyz from read-only pc.
// No __syncthreads, no RMWs, no acquire/release cache maintenance in the loop.
__global__ __launch_bounds__(FPS_THR, 1) void fps_kernel(const float* __restrict__ pc,
                                                         float* __restrict__ centers,
                                                         unsigned long long* __restrict__ slots) {
  const int blk = blockIdx.x;
  const int b = blk / FPS_NBLK, bb = blk % FPS_NBLK;
  const int tid = threadIdx.x;
  const int lane = tid & 63;
  const int wvg = bb * (FPS_THR / 64) + (tid >> 6);   // global wave id in batch: 0..63
  const float* pcb = pc + (size_t)b * NPTS * 3;

  __shared__ float kpts[96];

  float px[FPS_PPT], py[FPS_PPT], pz[FPS_PPT], mind[FPS_PPT];
  const int gbase = wvg * 1024;                        // 1024 points per wave
#pragma unroll
  for (int i = 0; i < FPS_PPT; ++i) {
    int g = gbase + i * 64 + lane;
    px[i] = pcb[3 * g]; py[i] = pcb[3 * g + 1]; pz[i] = pcb[3 * g + 2];
  }
  for (int i = tid; i < 96; i += FPS_THR) kpts[i] = pcb[i];
  __syncthreads();   // only barrier: kpts ready (density phase)

  unsigned long long* const slotb = slots + (size_t)b * KCP * 64;

  // one global argmax round: wave-reduce key, publish, poll 64 slots, reduce winner
  auto roundw = [&](unsigned long long key, int t) -> int {
#pragma unroll
    for (int off = 1; off < 64; off <<= 1) key = umaxll(key, __shfl_xor(key, off, 64));
    if (lane == 0)
      __hip_atomic_store(&slotb[(size_t)t * 64 + wvg], key, __ATOMIC_RELAXED, __HIP_MEMORY_SCOPE_AGENT);
    unsigned long long k2;
    do {
      k2 = __hip_atomic_load(&slotb[(size_t)t * 64 + lane], __ATOMIC_RELAXED, __HIP_MEMORY_SCOPE_AGENT);
    } while (__any(k2 == 0ull));
#pragma unroll
    for (int off = 1; off < 64; off <<= 1) k2 = umaxll(k2, __shfl_xor(k2, off, 64));
    return (int)(~(unsigned int)(k2 & 0xFFFFFFFFull));
  };

  // --- density over first 32 points, argmax -> first center (IEEE f32, op-for-op)
  unsigned long long bk = 0ull;
#pragma unroll
  for (int i = 0; i < FPS_PPT; ++i) {
    float acc = 0.f;
    for (int j = 0; j < 32; ++j) {
      float dx = __fsub_rn(px[i], kpts[3 * j]);
      float dy = __fsub_rn(py[i], kpts[3 * j + 1]);
      float dz = __fsub_rn(pz[i], kpts[3 * j + 2]);
      float ss = __fadd_rn(__fadd_rn(__fmul_rn(dx, dx), __fmul_rn(dy, dy)), __fmul_rn(dz, dz));
      float d = __fsqrt_rn(ss);
      float dd = __fadd_rn(__fmul_rn(d, d), 1e-6f);
      acc = __fadd_rn(acc, expf(__fdiv_rn(-0.02f, dd)));
    }
    float dens = __fdiv_rn(acc, 32.f);
    int g = gbase + i * 64 + lane;
    bk = umaxll(bk, ((unsigned long long)__float_as_uint(dens) << 32) | (unsigned int)(~g));
  }
  int widx = roundw(bk, 0);
  float cx = pcb[3 * widx], cy = pcb[3 * widx + 1], cz = pcb[3 * widx + 2];
  if (bb == 0 && tid == 0) {
    centers[(size_t)b * KCP * 3 + 0] = cx;
    centers[(size_t)b * KCP * 3 + 1] = cy;
    centers[(size_t)b * KCP * 3 + 2] = cz;
  }
#pragma unroll
  for (int i = 0; i < FPS_PPT; ++i) {
    float dx = __fsub_rn(px[i], cx), dy = __fsub_rn(py[i], cy), dz = __fsub_rn(pz[i], cz);
    mind[i] = __fsqrt_rn(__fadd_rn(__fadd_rn(__fmul_rn(dx, dx), __fmul_rn(dy, dy)), __fmul_rn(dz, dz)));
  }

  for (int t = 1; t < KCP; ++t) {
    bk = 0ull;
#pragma unroll
    for (int i = 0; i < FPS_PPT; ++i) {
      int g = gbase + i * 64 + lane;
      bk = umaxll(bk, ((unsigned long long)__float_as_uint(mind[i]) << 32) | (unsigned int)(~g));
    }
    widx = roundw(bk, t);
    cx = pcb[3 * widx]; cy = pcb[3 * widx + 1]; cz = pcb[3 * widx + 2];
    if (bb == 0 && tid == 0) {
      centers[((size_t)b * KCP + t) * 3 + 0] = cx;
      centers[((size_t)b * KCP + t) * 3 + 1] = cy;
      centers[((size_t)b * KCP + t) * 3 + 2] = cz;
    }
#pragma unroll
    for (int i = 0; i < FPS_PPT; ++i) {
      float dx = __fsub_rn(px[i], cx), dy = __fsub_rn(py[i], cy), dz = __fsub_rn(pz[i], cz);
      float d = __fsqrt_rn(__fadd_rn(__fadd_rn(__fmul_rn(dx, dx), __fmul_rn(dy, dy)), __fmul_rn(dz, dz)));
      mind[i] = fminf(mind[i], d);
    }
  }
}

// ---------------------------------------------------------------- point encoder + pos-emb -> x (B,K,256)
__global__ __launch_bounds__(128) void pe_kernel(const float* __restrict__ centers,
                                                 const float* __restrict__ w1, const float* __restrict__ b1,
                                                 const float* __restrict__ w2, const float* __restrict__ b2,
                                                 float* __restrict__ x) {
  const int p = blockIdx.x;      // b*K + k
  const int d = threadIdx.x;     // 0..127
  __shared__ float h[128];
  __shared__ float c[3];
  if (d < 3) c[d] = centers[(size_t)p * 3 + d];
  __syncthreads();
  float hv = b1[d];
#pragma unroll
  for (int j = 0; j < 3; ++j) hv += c[j] * w1[j * 128 + d];
  hv = fmaxf(hv, 0.f);
  h[d] = hv;
  __syncthreads();
  float f = b2[d];
  for (int j = 0; j < 128; ++j) f += h[j] * w2[j * 128 + d];
  x[(size_t)p * 256 + d] = f;
  if (d < 64) {
    float fr = expf(__fmul_rn((float)d, -0.14619587892025696f)); // -ln(10000)/63
    float ssum = 0.f, csum = 0.f;
#pragma unroll
    for (int a = 0; a < 3; ++a) {
      float e = __fmul_rn(c[a], fr);
      ssum += sinf(e); csum += cosf(e);
    }
    x[(size_t)p * 256 + 128 + d] = __fdiv_rn(ssum, 3.f);
    x[(size_t)p * 256 + 192 + d] = __fdiv_rn(csum, 3.f);
  }
}

// ---------------------------------------------------------------- tiled f32 GEMM: C = A(M,K)@W(K,N)+bias [relu]
__global__ __launch_bounds__(256) void gemm_kernel(const float* __restrict__ A, const float* __restrict__ W,
                                                   const float* __restrict__ bias, float* __restrict__ C,
                                                   int M, int Kd, int Nd, int relu) {
  __shared__ float As[16][65];
  __shared__ float Ws[16][65];
  const int bm = blockIdx.y * 64, bn = blockIdx.x * 64;
  const int tid = threadIdx.x;
  const int tx = tid & 15, ty = tid >> 4;
  float acc[4][4] = {};
  for (int k0 = 0; k0 < Kd; k0 += 16) {
#pragma unroll
    for (int i = 0; i < 4; ++i) {
      int f = tid + 256 * i; int k = f & 15, m = f >> 4;
      As[k][m] = A[(size_t)(bm + m) * Kd + k0 + k];
    }
#pragma unroll
    for (int i = 0; i < 4; ++i) {
      int f = tid + 256 * i; int n = f & 63, k = f >> 6;
      Ws[k][n] = W[(size_t)(k0 + k) * Nd + bn + n];
    }
    __syncthreads();
#pragma unroll
    for (int k = 0; k < 16; ++k) {
      float a[4], w[4];
#pragma unroll
      for (int i = 0; i < 4; ++i) a[i] = As[k][ty * 4 + i];
#pragma unroll
      for (int j = 0; j < 4; ++j) w[j] = Ws[k][tx * 4 + j];
#pragma unroll
      for (int i = 0; i < 4; ++i)
#pragma unroll
        for (int j = 0; j < 4; ++j) acc[i][j] += a[i] * w[j];
    }
    __syncthreads();
  }
#pragma unroll
  for (int i = 0; i < 4; ++i)
#pragma unroll
    for (int j = 0; j < 4; ++j) {
      float v = acc[i][j] + bias[bn + tx * 4 + j];
      if (relu) v = fmaxf(v, 0.f);
      C[(size_t)(bm + ty * 4 + i) * Nd + bn + tx * 4 + j] = v;
    }
}

// ---------------------------------------------------------------- flash attention for transformer (S=1024, dh=32, nh=8)
// grid (16 qtiles, 8 heads, 4 batches); block 256 = 64 queries x 4 dim-parts
__global__ __launch_bounds__(256, 1) void flash_kernel(const float* __restrict__ qkv, float* __restrict__ ao) {
  const int qt = blockIdx.x, h = blockIdx.y, b = blockIdx.z;
  const int tid = threadIdx.x;
  const int qi = tid >> 2, p = tid & 3;
  const int q0 = qt * 64;
  __shared__ float Kc[64][36];
  __shared__ float Vc[64][36];
  __shared__ float Sc[64][68];

  float4 q4[8];
  const float* qrow = qkv + (size_t)(b * 1024 + q0 + qi) * 768 + h * 32;
#pragma unroll
  for (int i = 0; i < 8; ++i) q4[i] = ((const float4*)qrow)[i];

  float o0[4] = {0, 0, 0, 0}, o1[4] = {0, 0, 0, 0};
  float m_cur = -INFINITY, l_part = 0.f;
  const int d0 = p * 8;

  for (int c0 = 0; c0 < 1024; c0 += 64) {
    for (int i = tid; i < 64 * 32; i += 256) {
      int j = i >> 5, d = i & 31;
      size_t row = (size_t)(b * 1024 + c0 + j) * 768;
      Kc[j][d] = qkv[row + 256 + h * 32 + d];
      Vc[j][d] = qkv[row + 512 + h * 32 + d];
    }
    __syncthreads();
    float sreg[16];
#pragma unroll 4
    for (int jj = 0; jj < 16; ++jj) {
      int j = p + 4 * jj;
      const float* kr = &Kc[j][0];
      float s = 0.f;
#pragma unroll
      for (int i = 0; i < 8; ++i) {
        float4 kv = *(const float4*)(kr + 4 * i);
        s += q4[i].x * kv.x + q4[i].y * kv.y + q4[i].z * kv.z + q4[i].w * kv.w;
      }
      sreg[jj] = s * 0.17677669529663687f; // 1/sqrt(32)
    }
    float cmax = sreg[0];
#pragma unroll
    for (int jj = 1; jj < 16; ++jj) cmax = fmaxf(cmax, sreg[jj]);
    cmax = fmaxf(cmax, __shfl_xor(cmax, 1, 64));
    cmax = fmaxf(cmax, __shfl_xor(cmax, 2, 64));
    float m_new = fmaxf(m_cur, cmax);
    float corr = expf(m_cur - m_new);
    l_part *= corr;
#pragma unroll
    for (int i = 0; i < 4; ++i) { o0[i] *= corr; o1[i] *= corr; }
#pragma unroll
    for (int jj = 0; jj < 16; ++jj) {
      float pv = expf(sreg[jj] - m_new);
      l_part += pv;
      Sc[qi][p + 4 * jj] = pv;
    }
    m_cur = m_new;
    // wave-coherent: row qi written only by the 4 lanes (same wave) that read it
    for (int j = 0; j < 64; ++j) {
      float pj = Sc[qi][j];
      float4 va = *(const float4*)(&Vc[j][d0]);
      float4 vb = *(const float4*)(&Vc[j][d0 + 4]);
      o0[0] += pj * va.x; o0[1] += pj * va.y; o0[2] += pj * va.z; o0[3] += pj * va.w;
      o1[0] += pj * vb.x; o1[1] += pj * vb.y; o1[2] += pj * vb.z; o1[3] += pj * vb.w;
    }
    __syncthreads();
  }
  float l2 = l_part + __shfl_xor(l_part, 1, 64);
  float lt = l2 + __shfl_xor(l2, 2, 64);
  float inv = 1.f / lt;
  float* orow = ao + (size_t)(b * 1024 + q0 + qi) * 256 + h * 32 + d0;
#pragma unroll
  for (int i = 0; i < 4; ++i) orow[i] = o0[i] * inv;
#pragma unroll
  for (int i = 0; i < 4; ++i) orow[4 + i] = o1[i] * inv;
}

// ---------------------------------------------------------------- fused residual + LayerNorm (rows of 256)
__global__ __launch_bounds__(256) void ln_kernel(const float* __restrict__ a, const float* __restrict__ r,
                                                 const float* __restrict__ sc, const float* __restrict__ bi,
                                                 float* __restrict__ out) {
  const int row = blockIdx.x * 4 + (threadIdx.x >> 6);
  const int lane = threadIdx.x & 63;
  const float* ar = a + (size_t)row * 256;
  const float* rr = r + (size_t)row * 256;
  float v[4];
#pragma unroll
  for (int i = 0; i < 4; ++i) v[i] = ar[lane + 64 * i] + rr[lane + 64 * i];
  float s = v[0] + v[1] + v[2] + v[3];
#pragma unroll
  for (int off = 32; off >= 1; off >>= 1) s += __shfl_xor(s, off, 64);
  float mean = s * (1.f / 256.f);
  float vs = 0.f;
#pragma unroll
  for (int i = 0; i < 4; ++i) { float d = v[i] - mean; vs += d * d; }
#pragma unroll
  for (int off = 32; off >= 1; off >>= 1) vs += __shfl_xor(vs, off, 64);
  float var = vs * (1.f / 256.f);
  float rstd = 1.f / sqrtf(var + 1e-5f);
  float* orow = out + (size_t)row * 256;
#pragma unroll
  for (int i = 0; i < 4; ++i) {
    int d = lane + 64 * i;
    orow[d] = (v[i] - mean) * rstd * sc[d] + bi[d];
  }
}

// ---------------------------------------------------------------- scatter x onto tri-planes (B,3,C,16,16)
__global__ __launch_bounds__(256) void scatter_kernel(const float* __restrict__ x,
                                                      const float* __restrict__ centers,
                                                      const float* __restrict__ Lv,
                                                      float* __restrict__ tri) {
  const int pnt = blockIdx.x;  // b*K + k
  const int b = pnt >> 10;
  const int tid = threadIdx.x;
  __shared__ int g[3];
  if (tid == 0) {
    float L = Lv[0];
    float half = __fmul_rn(L, 0.5f);
#pragma unroll
    for (int a = 0; a < 3; ++a) {
      float c = centers[(size_t)pnt * 3 + a];
      float t = __fmul_rn(__fdiv_rn(__fadd_rn(c, half), L), 16.f);
      int gi = (int)t;               // trunc toward zero, matches astype(int32)
      g[a] = min(15, max(0, gi));
    }
  }
  __syncthreads();
  const int gx = g[0], gy = g[1], gz = g[2];
  float v = x[(size_t)pnt * 256 + tid];
  float* trib = tri + (size_t)b * 3 * 256 * 256;
  atomicAdd(&trib[(0 * 256 + tid) * 256 + gy * 16 + gx], v);
  atomicAdd(&trib[(1 * 256 + tid) * 256 + gz * 16 + gy], v);
  atomicAdd(&trib[(2 * 256 + tid) * 256 + gz * 16 + gx], v);
}

// ---------------------------------------------------------------- direct conv 3x3 stride2 pad1 + bias + relu
template <int IC, int OC, int IH, int IW, int OH, int OW, int OCT, int ICC>
__global__ __launch_bounds__(256, 1) void conv_kernel(const float* __restrict__ in, const float* __restrict__ w,
                                                      const float* __restrict__ bias, float* __restrict__ out) {
  __shared__ float lin[ICC * IH * IW];
  const int n = blockIdx.x;
  const int oc = blockIdx.y * OCT + threadIdx.x / (OH * OW);
  const int sp = threadIdx.x % (OH * OW);
  const int oy = sp / OW, ox = sp % OW;
  const int iy0 = oy * 2 - 1, ix0 = ox * 2 - 1;
  float acc = 0.f;
  for (int c0 = 0; c0 < IC; c0 += ICC) {
    __syncthreads();
    for (int i = threadIdx.x; i < ICC * IH * IW; i += 256)
      lin[i] = in[((size_t)n * IC + c0) * (IH * IW) + i];
    __syncthreads();
    const float* wp = w + ((size_t)oc * IC + c0) * 9;
    for (int ic = 0; ic < ICC; ++ic) {
      const float* wr = wp + (size_t)ic * 9;
      const float* lr = lin + ic * IH * IW;
#pragma unroll
      for (int ky = 0; ky < 3; ++ky) {
        int iy = iy0 + ky;
        if (iy >= 0 && iy < IH) {
#pragma unroll
          for (int kx = 0; kx < 3; ++kx) {
            int ix = ix0 + kx;
            if (ix >= 0 && ix < IW) acc += lr[iy * IW + ix] * wr[ky * 3 + kx];
          }
        }
      }
    }
  }
  out[((size_t)n * OC + oc) * (OH * OW) + sp] = fmaxf(acc + bias[oc], 0.f);
}

// ---------------------------------------------------------------- bias init for atomic-accumulated outputs
__global__ void biasinit_kernel(float* __restrict__ out, const float* __restrict__ bias, int M, int N) {
  int i = blockIdx.x * 256 + threadIdx.x;
  if (i < M * N) out[i] = bias[i % N];
}

// ---------------------------------------------------------------- K-split matvec: out(M,N) += A(M,K)@W(K,N)
template <int M, int KC>
__global__ __launch_bounds__(256, 1) void matvec_kernel(const float* __restrict__ A, const float* __restrict__ W,
                                                        float* __restrict__ out, int Kd, int Nd) {
  __shared__ float Al[KC * M];
  const int tid = threadIdx.x;
  const int n = blockIdx.x * 256 + tid;
  const int k0 = blockIdx.y * KC;
  for (int i = tid; i < KC * M; i += 256) {
    int k = i / M, m = i - k * M;
    Al[i] = A[(size_t)m * Kd + k0 + k];
  }
  __syncthreads();
  float acc[M] = {};
  for (int k = 0; k < KC; ++k) {
    float wv = W[(size_t)(k0 + k) * Nd + n];
#pragma unroll
    for (int m = 0; m < M; ++m) acc[m] += Al[k * M + m] * wv;
  }
#pragma unroll
  for (int m = 0; m < M; ++m) atomicAdd(&out[(size_t)m * Nd + n], acc[m]);
}

// ---------------------------------------------------------------- final attention: S=3, dh=1024, 8 heads
__global__ __launch_bounds__(256) void attn3_kernel(const float* __restrict__ qkv, float* __restrict__ o) {
  const int b = blockIdx.x >> 3, h = blockIdx.x & 7;
  const float* base = qkv + (size_t)b * 3 * N3E;
  const int qo = h * 1024, ko = EDIM + h * 1024, vo = 2 * EDIM + h * 1024;
  float p[9] = {};
  for (int d = threadIdx.x; d < 1024; d += 256) {
    float q0 = base[qo + d], q1 = base[N3E + qo + d], q2 = base[2 * N3E + qo + d];
    float k0 = base[ko + d], k1 = base[N3E + ko + d], k2 = base[2 * N3E + ko + d];
    p[0] += q0 * k0; p[1] += q0 * k1; p[2] += q0 * k2;
    p[3] += q1 * k0; p[4] += q1 * k1; p[5] += q1 * k2;
    p[6] += q2 * k0; p[7] += q2 * k1; p[8] += q2 * k2;
  }
  __shared__ float red[4][9];
  __shared__ float aw[9];
  const int lane = threadIdx.x & 63, w = threadIdx.x >> 6;
#pragma unroll
  for (int e = 0; e < 9; ++e)
#pragma unroll
    for (int off = 32; off >= 1; off >>= 1) p[e] += __shfl_xor(p[e], off, 64);
  if (lane == 0)
#pragma unroll
    for (int e = 0; e < 9; ++e) red[w][e] = p[e];
  __syncthreads();
  if (threadIdx.x == 0) {
    float s[9];
#pragma unroll
    for (int e = 0; e < 9; ++e) s[e] = (red[0][e] + red[1][e] + red[2][e] + red[3][e]) / 32.f; // /sqrt(1024)
#pragma unroll
    for (int i = 0; i < 3; ++i) {
      float m = fmaxf(fmaxf(s[i * 3], s[i * 3 + 1]), s[i * 3 + 2]);
      float e0 = expf(s[i * 3] - m), e1 = expf(s[i * 3 + 1] - m), e2 = expf(s[i * 3 + 2] - m);
      float sm = e0 + e1 + e2;
      aw[i * 3] = e0 / sm; aw[i * 3 + 1] = e1 / sm; aw[i * 3 + 2] = e2 / sm;
    }
  }
  __syncthreads();
  for (int d = threadIdx.x; d < 1024; d += 256) {
    float v0 = base[vo + d], v1 = base[N3E + vo + d], v2 = base[2 * N3E + vo + d];
#pragma unroll
    for (int i = 0; i < 3; ++i)
      o[(size_t)(b * 3 + i) * EDIM + h * 1024 + d] = aw[i * 3] * v0 + aw[i * 3 + 1] * v1 + aw[i * 3 + 2] * v2;
  }
}

// ================================================================ launch
extern "C" void kernel_launch(void* const* d_in, const int* in_sizes, int n_in,
                              void* d_out, int out_size, void* d_ws, size_t ws_size,
                              hipStream_t stream) {
  const float* pc      = (const float*)d_in[0];
  const float* pe_w1   = (const float*)d_in[1];
  const float* pe_b1   = (const float*)d_in[2];
  const float* pe_w2   = (const float*)d_in[3];
  const float* pe_b2   = (const float*)d_in[4];
  const float* t_qkv_w = (const float*)d_in[5];
  const float* t_qkv_b = (const float*)d_in[6];
  const float* t_out_w = (const float*)d_in[7];
  const float* t_out_b = (const float*)d_in[8];
  const float* t_ln1_s = (const float*)d_in[9];
  const float* t_ln1_b = (const float*)d_in[10];
  const float* t_ff1_w = (const float*)d_in[11];
  const float* t_ff1_b = (const float*)d_in[12];
  const float* t_ff2_w = (const float*)d_in[13];
  const float* t_ff2_b = (const float*)d_in[14];
  const float* t_ln2_s = (const float*)d_in[15];
  const float* t_ln2_b = (const float*)d_in[16];
  const float* c1_w    = (const float*)d_in[17];
  const float* c1_b    = (const float*)d_in[18];
  const float* c2_w    = (const float*)d_in[19];
  const float* c2_b    = (const float*)d_in[20];
  const float* c3_w    = (const float*)d_in[21];
  const float* c3_b    = (const float*)d_in[22];
  const float* x_qkv_w = (const float*)d_in[23];
  const float* x_qkv_b = (const float*)d_in[24];
  const float* x_out_w = (const float*)d_in[25];
  const float* x_out_b = (const float*)d_in[26];
  float* outp = (float*)d_out;

  // workspace layout (~53 MB peak; post-transformer scratch aliases transformer scratch)
  char* wsp = (char*)d_ws;
  auto alloc = [&](size_t bytes) { char* q = wsp; wsp += (bytes + 255) & ~(size_t)255; return q; };
  float* centers = (float*)alloc((size_t)NBATCH * KCP * 3 * 4);
  float* pmax    = (float*)alloc(512 * 4);
  float* pmin    = (float*)alloc(512 * 4);
  float* Lv      = (float*)alloc(256);
  unsigned long long* slots = (unsigned long long*)alloc((size_t)NBATCH * KCP * 64 * 8);
  float* x  = (float*)alloc((size_t)4096 * 256 * 4);
  float* xb = (float*)alloc((size_t)4096 * 256 * 4);
  float* arena = (float*)wsp;
  // transformer views
  float* qkvb = arena;
  float* ao   = qkvb + (size_t)4096 * 768;
  float* po   = ao + (size_t)4096 * 256;
  float* ffh  = po + (size_t)4096 * 256;
  float* ffo  = ffh + (size_t)4096 * 1024;
  // post-phase views (alias arena; transformer scratch dead by then)
  float* tri  = arena;
  float* z1   = tri + (size_t)NBATCH * 3 * 256 * 256;
  float* z2   = z1 + (size_t)12 * 512 * 64;
  float* z3   = z2 + (size_t)12 * 1024 * 16;
  float* qkv2 = z3 + (size_t)12 * 8192;
  float* at2  = qkv2 + (size_t)12 * N3E;
  (void)in_sizes; (void)n_in; (void)out_size; (void)ws_size; (void)ffo;

  // FPS mailbox must be zero every call (graph replays don't re-poison ws)
  hipMemsetAsync(slots, 0, (size_t)NBATCH * KCP * 64 * 8, stream);

  redmm_kernel<<<512, 256, 0, stream>>>(pc, NBATCH * NPTS * 3, pmax, pmin);
  redfin_kernel<<<1, 256, 0, stream>>>(pmax, pmin, 512, Lv);

  fps_kernel<<<NBATCH * FPS_NBLK, FPS_THR, 0, stream>>>(pc, centers, slots);

  pe_kernel<<<NBATCH * KCP, 128, 0, stream>>>(centers, pe_w1, pe_b1, pe_w2, pe_b2, x);

  for (int l = 0; l < 2; ++l) {
    gemm_kernel<<<dim3(12, 64), 256, 0, stream>>>(x, t_qkv_w + (size_t)l * 256 * 768,
                                                  t_qkv_b + (size_t)l * 768, qkvb, 4096, 256, 768, 0);
    flash_kernel<<<dim3(16, 8, 4), 256, 0, stream>>>(qkvb, ao);
    gemm_kernel<<<dim3(4, 64), 256, 0, stream>>>(ao, t_out_w + (size_t)l * 256 * 256,
                                                 t_out_b + (size_t)l * 256, po, 4096, 256, 256, 0);
    ln_kernel<<<1024, 256, 0, stream>>>(x, po, t_ln1_s + (size_t)l * 256, t_ln1_b + (size_t)l * 256, xb);
    gemm_kernel<<<dim3(16, 64), 256, 0, stream>>>(xb, t_ff1_w + (size_t)l * 256 * 1024,
                                                  t_ff1_b + (size_t)l * 1024, ffh, 4096, 256, 1024, 1);
    gemm_kernel<<<dim3(4, 64), 256, 0, stream>>>(ffh, t_ff2_w + (size_t)l * 1024 * 256,
                                                 t_ff2_b + (size_t)l * 256, ffo, 4096, 1024, 256, 0);
    ln_kernel<<<1024, 256, 0, stream>>>(xb, ffo, t_ln2_s + (size_t)l * 256, t_ln2_b + (size_t)l * 256, x);
  }

  // scatter to tri-planes (zero first: atomic accumulation, and arena was reused)
  hipMemsetAsync(tri, 0, (size_t)NBATCH * 3 * 256 * 256 * 4, stream);
  scatter_kernel<<<NBATCH * KCP, 256, 0, stream>>>(x, centers, Lv, tri);

  conv_kernel<256, 512, 16, 16, 8, 8, 4, 32><<<dim3(12, 128), 256, 0, stream>>>(tri, c1_w, c1_b, z1);
  conv_kernel<512, 1024, 8, 8, 4, 4, 16, 128><<<dim3(12, 64), 256, 0, stream>>>(z1, c2_w, c2_b, z2);
  conv_kernel<1024, 2048, 4, 4, 2, 2, 64, 256><<<dim3(12, 32), 256, 0, stream>>>(z2, c3_w, c3_b, z3);

  biasinit_kernel<<<(12 * N3E + 255) / 256, 256, 0, stream>>>(qkv2, x_qkv_b, 12, N3E);
  matvec_kernel<12, 512><<<dim3(N3E / 256, 16), 256, 0, stream>>>(z3, x_qkv_w, qkv2, EDIM, N3E);

  attn3_kernel<<<32, 256, 0, stream>>>(qkv2, at2);

  biasinit_kernel<<<(12 * EDIM + 255) / 256, 256, 0, stream>>>(outp, x_out_b, 12, EDIM);
  matvec_kernel<12, 512><<<dim3(EDIM / 256, 16), 256, 0, stream>>>(at2, x_out_w, outp, EDIM, EDIM);
}

// Round 4
// 6000.514 us; speedup vs baseline: 1.1484x; 1.1484x over previous
//
#include <hip/hip_runtime.h>
#include <math.h>

// Problem constants
#define NPTS   65536
#define NBATCH 4
#define KCP    1024      // NCP centers
#define DM     256
#define FFD    1024
#define EDIM   8192      // E
#define N3E    24576     // 3*E

// FPS decomposition: 16 blocks/batch x 256 threads (4 waves); 64 publisher-waves
// per batch, each wave owns 1024 points (16/thread) held in registers.
#define FPS_NBLK 16
#define FPS_THR  256
#define FPS_PPT  16
#define HARV_MAX 8       // max winners harvested per global sync round
#define RING     16      // mailbox ring depth (rounds)

__device__ __forceinline__ unsigned long long umaxll(unsigned long long a, unsigned long long b) {
  return a > b ? a : b;
}

// ---------------------------------------------------------------- global min/max (for L)
__global__ __launch_bounds__(256) void redmm_kernel(const float* __restrict__ v, int n,
                                                    float* __restrict__ pmax, float* __restrict__ pmin) {
  float mx = -INFINITY, mn = INFINITY;
  for (int i = blockIdx.x * 256 + threadIdx.x; i < n; i += gridDim.x * 256) {
    float x = v[i]; mx = fmaxf(mx, x); mn = fminf(mn, x);
  }
#pragma unroll
  for (int off = 32; off >= 1; off >>= 1) {
    mx = fmaxf(mx, __shfl_xor(mx, off, 64));
    mn = fminf(mn, __shfl_xor(mn, off, 64));
  }
  __shared__ float smx[4], smn[4];
  int lane = threadIdx.x & 63, w = threadIdx.x >> 6;
  if (lane == 0) { smx[w] = mx; smn[w] = mn; }
  __syncthreads();
  if (threadIdx.x == 0) {
    pmax[blockIdx.x] = fmaxf(fmaxf(smx[0], smx[1]), fmaxf(smx[2], smx[3]));
    pmin[blockIdx.x] = fminf(fminf(smn[0], smn[1]), fminf(smn[2], smn[3]));
  }
}

__global__ __launch_bounds__(256) void redfin_kernel(const float* __restrict__ pmax,
                                                     const float* __restrict__ pmin, int nb,
                                                     float* __restrict__ Lv) {
  float mx = -INFINITY, mn = INFINITY;
  for (int i = threadIdx.x; i < nb; i += 256) { mx = fmaxf(mx, pmax[i]); mn = fminf(mn, pmin[i]); }
#pragma unroll
  for (int off = 32; off >= 1; off >>= 1) {
    mx = fmaxf(mx, __shfl_xor(mx, off, 64));
    mn = fminf(mn, __shfl_xor(mn, off, 64));
  }
  __shared__ float smx[4], smn[4];
  int lane = threadIdx.x & 63, w = threadIdx.x >> 6;
  if (lane == 0) { smx[w] = mx; smn[w] = mn; }
  __syncthreads();
  if (threadIdx.x == 0) {
    mx = fmaxf(fmaxf(smx[0], smx[1]), fmaxf(smx[2], smx[3]));
    mn = fminf(fminf(smn[0], smn[1]), fminf(smn[2], smn[3]));
    Lv[0] = __fsub_rn(mx, mn);
  }
}

// ---------------------------------------------------------------- FPS with candidate harvesting
// Per global round each wave publishes its top-4 (key,xyz). Every wave then runs
// an identical replicated mini-FPS over the 256 shared candidates, harvesting up
// to HARV_MAX true winners per sync: a candidate is a valid global winner while
// its updated key >= U (max over waves of published 4th-best key), since all
// non-listed points are < their wave's 4th-best and updates only decrease keys.
// Mailbox: ring of RING rounds, 64 slots x 128B; tag release / acquire-poll.
__global__ __launch_bounds__(FPS_THR, 1) void fps_kernel(const float* __restrict__ pc,
                                                         float* __restrict__ centers,
                                                         unsigned long long* __restrict__ slots) {
  const int blk = blockIdx.x;
  const int b = blk / FPS_NBLK, bb = blk % FPS_NBLK;
  const int tid = threadIdx.x;
  const int lane = tid & 63, wv = tid >> 6;
  const int wvg = bb * 4 + wv;                 // wave id in batch: 0..63
  const float* pcb = pc + (size_t)b * NPTS * 3;

  __shared__ float kpts[96];
  __shared__ float wlds[4][HARV_MAX][3];

  float px[FPS_PPT], py[FPS_PPT], pz[FPS_PPT], mind[FPS_PPT];
  const int gbase = wvg * 1024;                // 1024 points per wave
#pragma unroll
  for (int i = 0; i < FPS_PPT; ++i) {
    int g = gbase + i * 64 + lane;
    px[i] = pcb[3 * g]; py[i] = pcb[3 * g + 1]; pz[i] = pcb[3 * g + 2];
  }
  for (int i = tid; i < 96; i += FPS_THR) kpts[i] = pcb[i];
  __syncthreads();   // only barrier: kpts ready

  unsigned long long* const slotb = slots + (size_t)b * RING * 64 * 16;

  // butterfly argmax carrying xyz payload
  auto cred4 = [&](unsigned long long& k, float& x, float& y, float& z) {
#pragma unroll
    for (int off = 1; off < 64; off <<= 1) {
      unsigned long long ko = __shfl_xor(k, off, 64);
      float xo = __shfl_xor(x, off, 64);
      float yo = __shfl_xor(y, off, 64);
      float zo = __shfl_xor(z, off, 64);
      if (ko > k) { k = ko; x = xo; y = yo; z = zo; }
    }
  };

  // extract wave top-4 from tk/pxyz, publish round r, poll, read 256 candidates
  // (lane l holds wave l's 4 entries in ck/cx/cy/cz)
  auto pubpoll = [&](unsigned long long* tk, int r,
                     unsigned long long* ck, float* cx, float* cy, float* cz) {
    unsigned long long ek[4]; float ex[4], ey[4], ez[4];
#pragma unroll
    for (int g = 0; g < 4; ++g) {
      unsigned long long bk = 0ull; float bx = 0.f, by = 0.f, bz = 0.f;
#pragma unroll
      for (int i = 0; i < FPS_PPT; ++i)
        if (tk[i] > bk) { bk = tk[i]; bx = px[i]; by = py[i]; bz = pz[i]; }
      cred4(bk, bx, by, bz);
      ek[g] = bk; ex[g] = bx; ey[g] = by; ez[g] = bz;
#pragma unroll
      for (int i = 0; i < FPS_PPT; ++i) if (tk[i] == bk) tk[i] = 0ull;
    }
    unsigned long long* sp = slotb + (((size_t)(r & (RING - 1)) * 64) + wvg) * 16;
    if (lane == 0) {
      float* fp = (float*)sp;
#pragma unroll
      for (int e = 0; e < 4; ++e) {
        __hip_atomic_store(&sp[4 * e], ek[e], __ATOMIC_RELAXED, __HIP_MEMORY_SCOPE_AGENT);
        __hip_atomic_store(&fp[8 * e + 2], ex[e], __ATOMIC_RELAXED, __HIP_MEMORY_SCOPE_AGENT);
        __hip_atomic_store(&fp[8 * e + 3], ey[e], __ATOMIC_RELAXED, __HIP_MEMORY_SCOPE_AGENT);
        __hip_atomic_store(&fp[8 * e + 4], ez[e], __ATOMIC_RELAXED, __HIP_MEMORY_SCOPE_AGENT);
      }
      __hip_atomic_store(&sp[15], (unsigned long long)r, __ATOMIC_RELEASE, __HIP_MEMORY_SCOPE_AGENT);
    }
    const unsigned long long* spl = slotb + (((size_t)(r & (RING - 1)) * 64) + lane) * 16;
    unsigned long long tag;
    do {
      tag = __hip_atomic_load(&spl[15], __ATOMIC_ACQUIRE, __HIP_MEMORY_SCOPE_AGENT);
    } while (__any(tag != (unsigned long long)r));
    const float* fpl = (const float*)spl;
#pragma unroll
    for (int e = 0; e < 4; ++e) {
      ck[e] = __hip_atomic_load(&spl[4 * e], __ATOMIC_RELAXED, __HIP_MEMORY_SCOPE_AGENT);
      cx[e] = __hip_atomic_load(&fpl[8 * e + 2], __ATOMIC_RELAXED, __HIP_MEMORY_SCOPE_AGENT);
      cy[e] = __hip_atomic_load(&fpl[8 * e + 3], __ATOMIC_RELAXED, __HIP_MEMORY_SCOPE_AGENT);
      cz[e] = __hip_atomic_load(&fpl[8 * e + 4], __ATOMIC_RELAXED, __HIP_MEMORY_SCOPE_AGENT);
    }
  };

  // --- round 1: density over first 32 points (IEEE f32, op-for-op), argmax -> center 0
  unsigned long long tk[FPS_PPT];
#pragma unroll
  for (int i = 0; i < FPS_PPT; ++i) {
    float acc = 0.f;
    for (int j = 0; j < 32; ++j) {
      float dx = __fsub_rn(px[i], kpts[3 * j]);
      float dy = __fsub_rn(py[i], kpts[3 * j + 1]);
      float dz = __fsub_rn(pz[i], kpts[3 * j + 2]);
      float ss = __fadd_rn(__fadd_rn(__fmul_rn(dx, dx), __fmul_rn(dy, dy)), __fmul_rn(dz, dz));
      float d = __fsqrt_rn(ss);
      float dd = __fadd_rn(__fmul_rn(d, d), 1e-6f);
      acc = __fadd_rn(acc, expf(__fdiv_rn(-0.02f, dd)));
    }
    float dens = __fdiv_rn(acc, 32.f);
    int g = gbase + i * 64 + lane;
    tk[i] = ((unsigned long long)__float_as_uint(dens) << 32) | (unsigned int)(~g);
  }
  unsigned long long ck[4]; float cx[4], cy[4], cz[4];
  pubpoll(tk, 1, ck, cx, cy, cz);
  unsigned long long wk = 0ull; float wx = 0.f, wy = 0.f, wz = 0.f;
#pragma unroll
  for (int e = 0; e < 4; ++e)
    if (ck[e] > wk) { wk = ck[e]; wx = cx[e]; wy = cy[e]; wz = cz[e]; }
  cred4(wk, wx, wy, wz);
  if (wvg == 0 && lane == 0) {
    centers[(size_t)b * KCP * 3 + 0] = wx;
    centers[(size_t)b * KCP * 3 + 1] = wy;
    centers[(size_t)b * KCP * 3 + 2] = wz;
  }
#pragma unroll
  for (int i = 0; i < FPS_PPT; ++i) {
    float dx = __fsub_rn(px[i], wx), dy = __fsub_rn(py[i], wy), dz = __fsub_rn(pz[i], wz);
    mind[i] = __fsqrt_rn(__fadd_rn(__fadd_rn(__fmul_rn(dx, dx), __fmul_rn(dy, dy)), __fmul_rn(dz, dz)));
  }

  int t = 1, r = 2;
  while (t < KCP) {
#pragma unroll
    for (int i = 0; i < FPS_PPT; ++i) {
      int g = gbase + i * 64 + lane;
      tk[i] = ((unsigned long long)__float_as_uint(mind[i]) << 32) | (unsigned int)(~g);
    }
    pubpoll(tk, r, ck, cx, cy, cz);
    // U = max over waves of published 4th-best key (pre-update)
    unsigned long long u = ck[3];
#pragma unroll
    for (int off = 1; off < 64; off <<= 1) u = umaxll(u, __shfl_xor(u, off, 64));
    // replicated mini-FPS harvest
    int h = 0;
    while (true) {
      unsigned long long wk2 = 0ull; float wx2 = 0.f, wy2 = 0.f, wz2 = 0.f;
#pragma unroll
      for (int e = 0; e < 4; ++e)
        if (ck[e] > wk2) { wk2 = ck[e]; wx2 = cx[e]; wy2 = cy[e]; wz2 = cz[e]; }
      cred4(wk2, wx2, wy2, wz2);
      if (h > 0 && wk2 < u) break;   // h==0 pick is always the true global argmax
      if (wvg == 0 && lane == 0) {
        centers[((size_t)b * KCP + t) * 3 + 0] = wx2;
        centers[((size_t)b * KCP + t) * 3 + 1] = wy2;
        centers[((size_t)b * KCP + t) * 3 + 2] = wz2;
      }
      if (lane == 0) { wlds[wv][h][0] = wx2; wlds[wv][h][1] = wy2; wlds[wv][h][2] = wz2; }
#pragma unroll
      for (int e = 0; e < 4; ++e) {
        float dx = __fsub_rn(cx[e], wx2), dy = __fsub_rn(cy[e], wy2), dz = __fsub_rn(cz[e], wz2);
        float d = __fsqrt_rn(__fadd_rn(__fadd_rn(__fmul_rn(dx, dx), __fmul_rn(dy, dy)), __fmul_rn(dz, dz)));
        float ov = __uint_as_float((unsigned int)(ck[e] >> 32));
        float nv = fminf(ov, d);
        ck[e] = ((unsigned long long)__float_as_uint(nv) << 32) | (ck[e] & 0xFFFFFFFFull);
      }
      ++h; ++t;
      if (h == HARV_MAX || t == KCP) break;
    }
    // update own points against harvested winners
    for (int j = 0; j < h; ++j) {
      float wx3 = wlds[wv][j][0], wy3 = wlds[wv][j][1], wz3 = wlds[wv][j][2];
#pragma unroll
      for (int i = 0; i < FPS_PPT; ++i) {
        float dx = __fsub_rn(px[i], wx3), dy = __fsub_rn(py[i], wy3), dz = __fsub_rn(pz[i], wz3);
        float d = __fsqrt_rn(__fadd_rn(__fadd_rn(__fmul_rn(dx, dx), __fmul_rn(dy, dy)), __fmul_rn(dz, dz)));
        mind[i] = fminf(mind[i], d);
      }
    }
    ++r;
  }
}

// ---------------------------------------------------------------- point encoder + pos-emb -> x (B,K,256)
__global__ __launch_bounds__(128) void pe_kernel(const float* __restrict__ centers,
                                                 const float* __restrict__ w1, const float* __restrict__ b1,
                                                 const float* __restrict__ w2, const float* __restrict__ b2,
                                                 float* __restrict__ x) {
  const int p = blockIdx.x;      // b*K + k
  const int d = threadIdx.x;     // 0..127
  __shared__ float h[128];
  __shared__ float c[3];
  if (d < 3) c[d] = centers[(size_t)p * 3 + d];
  __syncthreads();
  float hv = b1[d];
#pragma unroll
  for (int j = 0; j < 3; ++j) hv += c[j] * w1[j * 128 + d];
  hv = fmaxf(hv, 0.f);
  h[d] = hv;
  __syncthreads();
  float f = b2[d];
  for (int j = 0; j < 128; ++j) f += h[j] * w2[j * 128 + d];
  x[(size_t)p * 256 + d] = f;
  if (d < 64) {
    float fr = expf(__fmul_rn((float)d, -0.14619587892025696f)); // -ln(10000)/63
    float ssum = 0.f, csum = 0.f;
#pragma unroll
    for (int a = 0; a < 3; ++a) {
      float e = __fmul_rn(c[a], fr);
      ssum += sinf(e); csum += cosf(e);
    }
    x[(size_t)p * 256 + 128 + d] = __fdiv_rn(ssum, 3.f);
    x[(size_t)p * 256 + 192 + d] = __fdiv_rn(csum, 3.f);
  }
}

// ---------------------------------------------------------------- tiled f32 GEMM: C = A(M,K)@W(K,N)+bias [relu]
__global__ __launch_bounds__(256) void gemm_kernel(const float* __restrict__ A, const float* __restrict__ W,
                                                   const float* __restrict__ bias, float* __restrict__ C,
                                                   int M, int Kd, int Nd, int relu) {
  __shared__ float As[16][65];
  __shared__ float Ws[16][65];
  const int bm = blockIdx.y * 64, bn = blockIdx.x * 64;
  const int tid = threadIdx.x;
  const int tx = tid & 15, ty = tid >> 4;
  float acc[4][4] = {};
  for (int k0 = 0; k0 < Kd; k0 += 16) {
#pragma unroll
    for (int i = 0; i < 4; ++i) {
      int f = tid + 256 * i; int k = f & 15, m = f >> 4;
      As[k][m] = A[(size_t)(bm + m) * Kd + k0 + k];
    }
#pragma unroll
    for (int i = 0; i < 4; ++i) {
      int f = tid + 256 * i; int n = f & 63, k = f >> 6;
      Ws[k][n] = W[(size_t)(k0 + k) * Nd + bn + n];
    }
    __syncthreads();
#pragma unroll
    for (int k = 0; k < 16; ++k) {
      float a[4], w[4];
#pragma unroll
      for (int i = 0; i < 4; ++i) a[i] = As[k][ty * 4 + i];
#pragma unroll
      for (int j = 0; j < 4; ++j) w[j] = Ws[k][tx * 4 + j];
#pragma unroll
      for (int i = 0; i < 4; ++i)
#pragma unroll
        for (int j = 0; j < 4; ++j) acc[i][j] += a[i] * w[j];
    }
    __syncthreads();
  }
#pragma unroll
  for (int i = 0; i < 4; ++i)
#pragma unroll
    for (int j = 0; j < 4; ++j) {
      float v = acc[i][j] + bias[bn + tx * 4 + j];
      if (relu) v = fmaxf(v, 0.f);
      C[(size_t)(bm + ty * 4 + i) * Nd + bn + tx * 4 + j] = v;
    }
}

// ---------------------------------------------------------------- flash attention for transformer (S=1024, dh=32, nh=8)
// grid (16 qtiles, 8 heads, 4 batches); block 256 = 64 queries x 4 dim-parts
__global__ __launch_bounds__(256, 1) void flash_kernel(const float* __restrict__ qkv, float* __restrict__ ao) {
  const int qt = blockIdx.x, h = blockIdx.y, b = blockIdx.z;
  const int tid = threadIdx.x;
  const int qi = tid >> 2, p = tid & 3;
  const int q0 = qt * 64;
  __shared__ float Kc[64][36];
  __shared__ float Vc[64][36];
  __shared__ float Sc[64][68];

  float4 q4[8];
  const float* qrow = qkv + (size_t)(b * 1024 + q0 + qi) * 768 + h * 32;
#pragma unroll
  for (int i = 0; i < 8; ++i) q4[i] = ((const float4*)qrow)[i];

  float o0[4] = {0, 0, 0, 0}, o1[4] = {0, 0, 0, 0};
  float m_cur = -INFINITY, l_part = 0.f;
  const int d0 = p * 8;

  for (int c0 = 0; c0 < 1024; c0 += 64) {
    for (int i = tid; i < 64 * 32; i += 256) {
      int j = i >> 5, d = i & 31;
      size_t row = (size_t)(b * 1024 + c0 + j) * 768;
      Kc[j][d] = qkv[row + 256 + h * 32 + d];
      Vc[j][d] = qkv[row + 512 + h * 32 + d];
    }
    __syncthreads();
    float sreg[16];
#pragma unroll 4
    for (int jj = 0; jj < 16; ++jj) {
      int j = p + 4 * jj;
      const float* kr = &Kc[j][0];
      float s = 0.f;
#pragma unroll
      for (int i = 0; i < 8; ++i) {
        float4 kv = *(const float4*)(kr + 4 * i);
        s += q4[i].x * kv.x + q4[i].y * kv.y + q4[i].z * kv.z + q4[i].w * kv.w;
      }
      sreg[jj] = s * 0.17677669529663687f; // 1/sqrt(32)
    }
    float cmax = sreg[0];
#pragma unroll
    for (int jj = 1; jj < 16; ++jj) cmax = fmaxf(cmax, sreg[jj]);
    cmax = fmaxf(cmax, __shfl_xor(cmax, 1, 64));
    cmax = fmaxf(cmax, __shfl_xor(cmax, 2, 64));
    float m_new = fmaxf(m_cur, cmax);
    float corr = expf(m_cur - m_new);
    l_part *= corr;
#pragma unroll
    for (int i = 0; i < 4; ++i) { o0[i] *= corr; o1[i] *= corr; }
#pragma unroll
    for (int jj = 0; jj < 16; ++jj) {
      float pv = expf(sreg[jj] - m_new);
      l_part += pv;
      Sc[qi][p + 4 * jj] = pv;
    }
    m_cur = m_new;
    // wave-coherent: row qi written only by the 4 lanes (same wave) that read it
    for (int j = 0; j < 64; ++j) {
      float pj = Sc[qi][j];
      float4 va = *(const float4*)(&Vc[j][d0]);
      float4 vb = *(const float4*)(&Vc[j][d0 + 4]);
      o0[0] += pj * va.x; o0[1] += pj * va.y; o0[2] += pj * va.z; o0[3] += pj * va.w;
      o1[0] += pj * vb.x; o1[1] += pj * vb.y; o1[2] += pj * vb.z; o1[3] += pj * vb.w;
    }
    __syncthreads();
  }
  float l2 = l_part + __shfl_xor(l_part, 1, 64);
  float lt = l2 + __shfl_xor(l2, 2, 64);
  float inv = 1.f / lt;
  float* orow = ao + (size_t)(b * 1024 + q0 + qi) * 256 + h * 32 + d0;
#pragma unroll
  for (int i = 0; i < 4; ++i) orow[i] = o0[i] * inv;
#pragma unroll
  for (int i = 0; i < 4; ++i) orow[4 + i] = o1[i] * inv;
}

// ---------------------------------------------------------------- fused residual + LayerNorm (rows of 256)
__global__ __launch_bounds__(256) void ln_kernel(const float* __restrict__ a, const float* __restrict__ r,
                                                 const float* __restrict__ sc, const float* __restrict__ bi,
                                                 float* __restrict__ out) {
  const int row = blockIdx.x * 4 + (threadIdx.x >> 6);
  const int lane = threadIdx.x & 63;
  const float* ar = a + (size_t)row * 256;
  const float* rr = r + (size_t)row * 256;
  float v[4];
#pragma unroll
  for (int i = 0; i < 4; ++i) v[i] = ar[lane + 64 * i] + rr[lane + 64 * i];
  float s = v[0] + v[1] + v[2] + v[3];
#pragma unroll
  for (int off = 32; off >= 1; off >>= 1) s += __shfl_xor(s, off, 64);
  float mean = s * (1.f / 256.f);
  float vs = 0.f;
#pragma unroll
  for (int i = 0; i < 4; ++i) { float d = v[i] - mean; vs += d * d; }
#pragma unroll
  for (int off = 32; off >= 1; off >>= 1) vs += __shfl_xor(vs, off, 64);
  float var = vs * (1.f / 256.f);
  float rstd = 1.f / sqrtf(var + 1e-5f);
  float* orow = out + (size_t)row * 256;
#pragma unroll
  for (int i = 0; i < 4; ++i) {
    int d = lane + 64 * i;
    orow[d] = (v[i] - mean) * rstd * sc[d] + bi[d];
  }
}

// ---------------------------------------------------------------- scatter x onto tri-planes (B,3,C,16,16)
__global__ __launch_bounds__(256) void scatter_kernel(const float* __restrict__ x,
                                                      const float* __restrict__ centers,
                                                      const float* __restrict__ Lv,
                                                      float* __restrict__ tri) {
  const int pnt = blockIdx.x;  // b*K + k
  const int b = pnt >> 10;
  const int tid = threadIdx.x;
  __shared__ int g[3];
  if (tid == 0) {
    float L = Lv[0];
    float half = __fmul_rn(L, 0.5f);
#pragma unroll
    for (int a = 0; a < 3; ++a) {
      float c = centers[(size_t)pnt * 3 + a];
      float t = __fmul_rn(__fdiv_rn(__fadd_rn(c, half), L), 16.f);
      int gi = (int)t;               // trunc toward zero, matches astype(int32)
      g[a] = min(15, max(0, gi));
    }
  }
  __syncthreads();
  const int gx = g[0], gy = g[1], gz = g[2];
  float v = x[(size_t)pnt * 256 + tid];
  float* trib = tri + (size_t)b * 3 * 256 * 256;
  atomicAdd(&trib[(0 * 256 + tid) * 256 + gy * 16 + gx], v);
  atomicAdd(&trib[(1 * 256 + tid) * 256 + gz * 16 + gy], v);
  atomicAdd(&trib[(2 * 256 + tid) * 256 + gz * 16 + gx], v);
}

// ---------------------------------------------------------------- direct conv 3x3 stride2 pad1 + bias + relu
template <int IC, int OC, int IH, int IW, int OH, int OW, int OCT, int ICC>
__global__ __launch_bounds__(256, 1) void conv_kernel(const float* __restrict__ in, const float* __restrict__ w,
                                                      const float* __restrict__ bias, float* __restrict__ out) {
  __shared__ float lin[ICC * IH * IW];
  const int n = blockIdx.x;
  const int oc = blockIdx.y * OCT + threadIdx.x / (OH * OW);
  const int sp = threadIdx.x % (OH * OW);
  const int oy = sp / OW, ox = sp % OW;
  const int iy0 = oy * 2 - 1, ix0 = ox * 2 - 1;
  float acc = 0.f;
  for (int c0 = 0; c0 < IC; c0 += ICC) {
    __syncthreads();
    for (int i = threadIdx.x; i < ICC * IH * IW; i += 256)
      lin[i] = in[((size_t)n * IC + c0) * (IH * IW) + i];
    __syncthreads();
    const float* wp = w + ((size_t)oc * IC + c0) * 9;
    for (int ic = 0; ic < ICC; ++ic) {
      const float* wr = wp + (size_t)ic * 9;
      const float* lr = lin + ic * IH * IW;
#pragma unroll
      for (int ky = 0; ky < 3; ++ky) {
        int iy = iy0 + ky;
        if (iy >= 0 && iy < IH) {
#pragma unroll
          for (int kx = 0; kx < 3; ++kx) {
            int ix = ix0 + kx;
            if (ix >= 0 && ix < IW) acc += lr[iy * IW + ix] * wr[ky * 3 + kx];
          }
        }
      }
    }
  }
  out[((size_t)n * OC + oc) * (OH * OW) + sp] = fmaxf(acc + bias[oc], 0.f);
}

// ---------------------------------------------------------------- bias init for atomic-accumulated outputs
__global__ void biasinit_kernel(float* __restrict__ out, const float* __restrict__ bias, int M, int N) {
  int i = blockIdx.x * 256 + threadIdx.x;
  if (i < M * N) out[i] = bias[i % N];
}

// ---------------------------------------------------------------- K-split matvec: out(M,N) += A(M,K)@W(K,N)
template <int M, int KC>
__global__ __launch_bounds__(256, 1) void matvec_kernel(const float* __restrict__ A, const float* __restrict__ W,
                                                        float* __restrict__ out, int Kd, int Nd) {
  __shared__ float Al[KC * M];
  const int tid = threadIdx.x;
  const int n = blockIdx.x * 256 + tid;
  const int k0 = blockIdx.y * KC;
  for (int i = tid; i < KC * M; i += 256) {
    int k = i / M, m = i - k * M;
    Al[i] = A[(size_t)m * Kd + k0 + k];
  }
  __syncthreads();
  float acc[M] = {};
  for (int k = 0; k < KC; ++k) {
    float wv = W[(size_t)(k0 + k) * Nd + n];
#pragma unroll
    for (int m = 0; m < M; ++m) acc[m] += Al[k * M + m] * wv;
  }
#pragma unroll
  for (int m = 0; m < M; ++m) atomicAdd(&out[(size_t)m * Nd + n], acc[m]);
}

// ---------------------------------------------------------------- final attention: S=3, dh=1024, 8 heads
__global__ __launch_bounds__(256) void attn3_kernel(const float* __restrict__ qkv, float* __restrict__ o) {
  const int b = blockIdx.x >> 3, h = blockIdx.x & 7;
  const float* base = qkv + (size_t)b * 3 * N3E;
  const int qo = h * 1024, ko = EDIM + h * 1024, vo = 2 * EDIM + h * 1024;
  float p[9] = {};
  for (int d = threadIdx.x; d < 1024; d += 256) {
    float q0 = base[qo + d], q1 = base[N3E + qo + d], q2 = base[2 * N3E + qo + d];
    float k0 = base[ko + d], k1 = base[N3E + ko + d], k2 = base[2 * N3E + ko + d];
    p[0] += q0 * k0; p[1] += q0 * k1; p[2] += q0 * k2;
    p[3] += q1 * k0; p[4] += q1 * k1; p[5] += q1 * k2;
    p[6] += q2 * k0; p[7] += q2 * k1; p[8] += q2 * k2;
  }
  __shared__ float red[4][9];
  __shared__ float aw[9];
  const int lane = threadIdx.x & 63, w = threadIdx.x >> 6;
#pragma unroll
  for (int e = 0; e < 9; ++e)
#pragma unroll
    for (int off = 32; off >= 1; off >>= 1) p[e] += __shfl_xor(p[e], off, 64);
  if (lane == 0)
#pragma unroll
    for (int e = 0; e < 9; ++e) red[w][e] = p[e];
  __syncthreads();
  if (threadIdx.x == 0) {
    float s[9];
#pragma unroll
    for (int e = 0; e < 9; ++e) s[e] = (red[0][e] + red[1][e] + red[2][e] + red[3][e]) / 32.f; // /sqrt(1024)
#pragma unroll
    for (int i = 0; i < 3; ++i) {
      float m = fmaxf(fmaxf(s[i * 3], s[i * 3 + 1]), s[i * 3 + 2]);
      float e0 = expf(s[i * 3] - m), e1 = expf(s[i * 3 + 1] - m), e2 = expf(s[i * 3 + 2] - m);
      float sm = e0 + e1 + e2;
      aw[i * 3] = e0 / sm; aw[i * 3 + 1] = e1 / sm; aw[i * 3 + 2] = e2 / sm;
    }
  }
  __syncthreads();
  for (int d = threadIdx.x; d < 1024; d += 256) {
    float v0 = base[vo + d], v1 = base[N3E + vo + d], v2 = base[2 * N3E + vo + d];
#pragma unroll
    for (int i = 0; i < 3; ++i)
      o[(size_t)(b * 3 + i) * EDIM + h * 1024 + d] = aw[i * 3] * v0 + aw[i * 3 + 1] * v1 + aw[i * 3 + 2] * v2;
  }
}

// ================================================================ launch
extern "C" void kernel_launch(void* const* d_in, const int* in_sizes, int n_in,
                              void* d_out, int out_size, void* d_ws, size_t ws_size,
                              hipStream_t stream) {
  const float* pc      = (const float*)d_in[0];
  const float* pe_w1   = (const float*)d_in[1];
  const float* pe_b1   = (const float*)d_in[2];
  const float* pe_w2   = (const float*)d_in[3];
  const float* pe_b2   = (const float*)d_in[4];
  const float* t_qkv_w = (const float*)d_in[5];
  const float* t_qkv_b = (const float*)d_in[6];
  const float* t_out_w = (const float*)d_in[7];
  const float* t_out_b = (const float*)d_in[8];
  const float* t_ln1_s = (const float*)d_in[9];
  const float* t_ln1_b = (const float*)d_in[10];
  const float* t_ff1_w = (const float*)d_in[11];
  const float* t_ff1_b = (const float*)d_in[12];
  const float* t_ff2_w = (const float*)d_in[13];
  const float* t_ff2_b = (const float*)d_in[14];
  const float* t_ln2_s = (const float*)d_in[15];
  const float* t_ln2_b = (const float*)d_in[16];
  const float* c1_w    = (const float*)d_in[17];
  const float* c1_b    = (const float*)d_in[18];
  const float* c2_w    = (const float*)d_in[19];
  const float* c2_b    = (const float*)d_in[20];
  const float* c3_w    = (const float*)d_in[21];
  const float* c3_b    = (const float*)d_in[22];
  const float* x_qkv_w = (const float*)d_in[23];
  const float* x_qkv_b = (const float*)d_in[24];
  const float* x_out_w = (const float*)d_in[25];
  const float* x_out_b = (const float*)d_in[26];
  float* outp = (float*)d_out;

  // workspace layout (~52 MB peak; post-transformer scratch aliases transformer scratch)
  char* wsp = (char*)d_ws;
  auto alloc = [&](size_t bytes) { char* q = wsp; wsp += (bytes + 255) & ~(size_t)255; return q; };
  float* centers = (float*)alloc((size_t)NBATCH * KCP * 3 * 4);
  float* pmax    = (float*)alloc(512 * 4);
  float* pmin    = (float*)alloc(512 * 4);
  float* Lv      = (float*)alloc(256);
  unsigned long long* slots = (unsigned long long*)alloc((size_t)NBATCH * RING * 64 * 128);
  float* x  = (float*)alloc((size_t)4096 * 256 * 4);
  float* xb = (float*)alloc((size_t)4096 * 256 * 4);
  float* arena = (float*)wsp;
  // transformer views
  float* qkvb = arena;
  float* ao   = qkvb + (size_t)4096 * 768;
  float* po   = ao + (size_t)4096 * 256;
  float* ffh  = po + (size_t)4096 * 256;
  float* ffo  = ffh + (size_t)4096 * 1024;
  // post-phase views (alias arena; transformer scratch dead by then)
  float* tri  = arena;
  float* z1   = tri + (size_t)NBATCH * 3 * 256 * 256;
  float* z2   = z1 + (size_t)12 * 512 * 64;
  float* z3   = z2 + (size_t)12 * 1024 * 16;
  float* qkv2 = z3 + (size_t)12 * 8192;
  float* at2  = qkv2 + (size_t)12 * N3E;
  (void)in_sizes; (void)n_in; (void)out_size; (void)ws_size; (void)ffo;

  // FPS mailbox ring must be zero every call (tags poll against round numbers)
  hipMemsetAsync(slots, 0, (size_t)NBATCH * RING * 64 * 128, stream);

  redmm_kernel<<<512, 256, 0, stream>>>(pc, NBATCH * NPTS * 3, pmax, pmin);
  redfin_kernel<<<1, 256, 0, stream>>>(pmax, pmin, 512, Lv);

  fps_kernel<<<NBATCH * FPS_NBLK, FPS_THR, 0, stream>>>(pc, centers, slots);

  pe_kernel<<<NBATCH * KCP, 128, 0, stream>>>(centers, pe_w1, pe_b1, pe_w2, pe_b2, x);

  for (int l = 0; l < 2; ++l) {
    gemm_kernel<<<dim3(12, 64), 256, 0, stream>>>(x, t_qkv_w + (size_t)l * 256 * 768,
                                                  t_qkv_b + (size_t)l * 768, qkvb, 4096, 256, 768, 0);
    flash_kernel<<<dim3(16, 8, 4), 256, 0, stream>>>(qkvb, ao);
    gemm_kernel<<<dim3(4, 64), 256, 0, stream>>>(ao, t_out_w + (size_t)l * 256 * 256,
                                                 t_out_b + (size_t)l * 256, po, 4096, 256, 256, 0);
    ln_kernel<<<1024, 256, 0, stream>>>(x, po, t_ln1_s + (size_t)l * 256, t_ln1_b + (size_t)l * 256, xb);
    gemm_kernel<<<dim3(16, 64), 256, 0, stream>>>(xb, t_ff1_w + (size_t)l * 256 * 1024,
                                                  t_ff1_b + (size_t)l * 1024, ffh, 4096, 256, 1024, 1);
    gemm_kernel<<<dim3(4, 64), 256, 0, stream>>>(ffh, t_ff2_w + (size_t)l * 1024 * 256,
                                                 t_ff2_b + (size_t)l * 256, ffo, 4096, 1024, 256, 0);
    ln_kernel<<<1024, 256, 0, stream>>>(xb, ffo, t_ln2_s + (size_t)l * 256, t_ln2_b + (size_t)l * 256, x);
  }

  // scatter to tri-planes (zero first: atomic accumulation, and arena was reused)
  hipMemsetAsync(tri, 0, (size_t)NBATCH * 3 * 256 * 256 * 4, stream);
  scatter_kernel<<<NBATCH * KCP, 256, 0, stream>>>(x, centers, Lv, tri);

  conv_kernel<256, 512, 16, 16, 8, 8, 4, 32><<<dim3(12, 128), 256, 0, stream>>>(tri, c1_w, c1_b, z1);
  conv_kernel<512, 1024, 8, 8, 4, 4, 16, 128><<<dim3(12, 64), 256, 0, stream>>>(z1, c2_w, c2_b, z2);
  conv_kernel<1024, 2048, 4, 4, 2, 2, 64, 256><<<dim3(12, 32), 256, 0, stream>>>(z2, c3_w, c3_b, z3);

  biasinit_kernel<<<(12 * N3E + 255) / 256, 256, 0, stream>>>(qkv2, x_qkv_b, 12, N3E);
  matvec_kernel<12, 512><<<dim3(N3E / 256, 16), 256, 0, stream>>>(z3, x_qkv_w, qkv2, EDIM, N3E);

  attn3_kernel<<<32, 256, 0, stream>>>(qkv2, at2);

  biasinit_kernel<<<(12 * EDIM + 255) / 256, 256, 0, stream>>>(outp, x_out_b, 12, EDIM);
  matvec_kernel<12, 512><<<dim3(EDIM / 256, 16), 256, 0, stream>>>(at2, x_out_w, outp, EDIM, EDIM);
}